// Round 21
// baseline (297.204 us; speedup 1.0000x reference)
//
#include <hip/hip_runtime.h>

#define N_NODES 131072
#define N_EDGES 2097152
#define N_GRAPHS 128
#define POOL_NPB 256       // nodes per block in k_pool
#define NB 256             // buckets (both src- and dst-binning)
#define BUCKET_SHIFT 9     // 512 nodes per bucket
#define BUCKET_CAP 9728    // max edges per bucket (mean 8192, +17 sigma)
#define BIN_EPT 8          // edges per thread per pass in k_bin (2048/block, 1024 blocks = 4/CU)

__device__ __forceinline__ float bf2f(unsigned short b) {
  return __uint_as_float(((unsigned int)b) << 16);
}
__device__ __forceinline__ unsigned short f2bf(float f) {
  unsigned int u = __float_as_uint(f);
  return (unsigned short)((u + 0x7FFFu + ((u >> 16) & 1u)) >> 16);  // RTNE
}
__device__ __forceinline__ unsigned int pack2bf(float a, float b) {
  return (unsigned int)f2bf(a) | ((unsigned int)f2bf(b) << 16);
}

// ---------------- bucket cursor init ----------------
__global__ __launch_bounds__(256) void k_init_buckets(int* __restrict__ cursor_d,
                                                      int* __restrict__ cursor_s) {
  int i = threadIdx.x;
  cursor_d[i] = i * BUCKET_CAP;
  cursor_s[i] = i * BUCKET_CAP;
}

// ---------------- phase A: bin edges (two-pass, zero per-edge global atomics) ----
__global__ __launch_bounds__(256) void k_bin(const int* __restrict__ src,
                                             const int* __restrict__ dst,
                                             int* __restrict__ cursor_d,
                                             int* __restrict__ cursor_s,
                                             unsigned int* __restrict__ recs_d,
                                             unsigned short* __restrict__ recs_s) {
  __shared__ int hd[NB];
  __shared__ int hs[NB];
  const int t = threadIdx.x;
  const int e0 = blockIdx.x * (256 * BIN_EPT);
  hd[t] = 0; hs[t] = 0;
  __syncthreads();
#pragma unroll 4
  for (int k = 0; k < BIN_EPT; ++k) {
    int e = e0 + k * 256 + t;
    atomicAdd(&hd[dst[e] >> BUCKET_SHIFT], 1);
    atomicAdd(&hs[src[e] >> BUCKET_SHIFT], 1);
  }
  __syncthreads();
  { int c = hd[t]; hd[t] = c ? atomicAdd(&cursor_d[t], c) : 0; }
  { int c = hs[t]; hs[t] = c ? atomicAdd(&cursor_s[t], c) : 0; }
  __syncthreads();
#pragma unroll 4
  for (int k = 0; k < BIN_EPT; ++k) {
    int e = e0 + k * 256 + t;      // re-read (L1/L2 hot)
    int s = src[e];
    int d = dst[e];
    int pd = atomicAdd(&hd[d >> BUCKET_SHIFT], 1);
    recs_d[pd] = ((unsigned int)s << BUCKET_SHIFT) | (unsigned int)(d & 511);
    int ps = atomicAdd(&hs[s >> BUCKET_SHIFT], 1);
    recs_s[ps] = (unsigned short)(s & 511);
  }
}

// ---------------- bucket base: exclusive scan of dst-bucket counts ----------------
__global__ __launch_bounds__(256) void k_bucket_scan(const int* __restrict__ cursor_d,
                                                     int* __restrict__ bucket_base,
                                                     int* __restrict__ row_start) {
  __shared__ int tmp[256];
  int t = threadIdx.x;
  int c = cursor_d[t] - t * BUCKET_CAP;
  tmp[t] = c;
  __syncthreads();
  for (int off = 1; off < 256; off <<= 1) {
    int x = (t >= off) ? tmp[t - off] : 0;
    __syncthreads();
    tmp[t] += x;
    __syncthreads();
  }
  bucket_base[t] = tmp[t] - c;
  if (t == 0) row_start[N_NODES] = N_EDGES;
}

// ---------------- fused graph-finalize: fill2 (blocks<NB) + outdeg (blocks>=NB) --
// Blocks 0..NB-1: per-dst-bucket indeg hist -> row_start/dst_norm + LDS-cursor
// CSR fill. Blocks NB..2NB-1: per-src-bucket outdeg hist -> src_norm. The two
// halves are independent; fusing lets them co-schedule across CUs instead of
// running as two serialized short dispatches.
__global__ __launch_bounds__(512) void k_graph(const unsigned int* __restrict__ recs_d,
                                               const int* __restrict__ cursor_d,
                                               const unsigned short* __restrict__ recs_s,
                                               const int* __restrict__ cursor_s,
                                               const int* __restrict__ bucket_base,
                                               int* __restrict__ row_start,
                                               float* __restrict__ src_norm,
                                               float* __restrict__ dst_norm,
                                               int* __restrict__ csr_src) {
  __shared__ int hist[512];
  __shared__ int lcur[512];
  const int t = threadIdx.x;
  if (blockIdx.x < NB) {
    // ---- dst-bucket: indeg + row_start + dst_norm + CSR fill ----
    const int b = blockIdx.x;
    hist[t] = 0;
    __syncthreads();
    const int beg = b * BUCKET_CAP;
    const int end = cursor_d[b];
    for (int i = beg + t; i < end; i += 512) atomicAdd(&hist[recs_d[i] & 511], 1);
    __syncthreads();
    int deg = hist[t];
    lcur[t] = deg;
    __syncthreads();
    for (int off = 1; off < 512; off <<= 1) {
      int x = (t >= off) ? lcur[t - off] : 0;
      __syncthreads();
      lcur[t] += x;
      __syncthreads();
    }
    int rs = bucket_base[b] + lcur[t] - deg;
    row_start[b * 512 + t] = rs;
    int dd = deg < 1 ? 1 : deg;
    dst_norm[b * 512 + t] = 1.0f / sqrtf((float)dd);
    lcur[t] = rs;
    __syncthreads();
    for (int i = beg + t; i < end; i += 512) {
      unsigned int r = recs_d[i];
      int p = atomicAdd(&lcur[r & 511], 1);
      csr_src[p] = (int)(r >> BUCKET_SHIFT);
    }
  } else {
    // ---- src-bucket: outdeg -> src_norm ----
    const int b = blockIdx.x - NB;
    hist[t] = 0;
    __syncthreads();
    const int beg = b * BUCKET_CAP;
    const int end = cursor_s[b];
    for (int i = beg + t; i < end; i += 512) atomicAdd(&hist[recs_s[i]], 1);
    __syncthreads();
    int od = hist[t]; if (od < 1) od = 1;
    src_norm[b * 512 + t] = 1.0f / sqrtf((float)od);
  }
}

// ---------------- GEMM v9: 8x8 register tile, 1-wave blocks, bf16 output --------
template <int DIN, int DOUT>
__global__ __launch_bounds__(64) void k_gemm_v9(const float* __restrict__ h,
                                                const float* __restrict__ src_norm,
                                                const float* __restrict__ W,
                                                unsigned short* __restrict__ out) {
  constexpr int KC   = 32;
  constexpr int ROWS = 64;
  constexpr int HF4  = KC * ROWS / 4;
  constexpr int WF4  = KC * DOUT / 4;
  __shared__ float hT[KC][ROWS];
  __shared__ float Ws[KC][DOUT];

  const int t  = threadIdx.x;
  const int rowBase = blockIdx.x * ROWS;
  const int tr = t & 7;
  const int tc = t >> 3;

  float acc[8][8];
#pragma unroll
  for (int i = 0; i < 8; ++i)
#pragma unroll
    for (int j = 0; j < 8; ++j) acc[i][j] = 0.0f;

  for (int kc = 0; kc < DIN; kc += KC) {
#pragma unroll
    for (int p = 0; p < HF4 / 64; ++p) {
      int f = t + p * 64;
      int rg = f >> 3;
      int ks = (f & 7) * 4;
      float4 v = *reinterpret_cast<const float4*>(&h[(size_t)(rowBase + rg) * DIN + kc + ks]);
      hT[ks + 0][rg ^ ((((ks + 0) >> 3) & 3) << 3)] = v.x;
      hT[ks + 1][rg ^ ((((ks + 1) >> 3) & 3) << 3)] = v.y;
      hT[ks + 2][rg ^ ((((ks + 2) >> 3) & 3) << 3)] = v.z;
      hT[ks + 3][rg ^ ((((ks + 3) >> 3) & 3) << 3)] = v.w;
    }
#pragma unroll
    for (int p = 0; p < WF4 / 64; ++p) {
      int idx = (t + p * 64) * 4;
      *reinterpret_cast<float4*>(&Ws[0][0] + idx) =
          *reinterpret_cast<const float4*>(&W[(size_t)kc * DOUT + idx]);
    }
    __syncthreads();
#pragma unroll
    for (int kk = 0; kk < KC; ++kk) {
      const int swz = ((kk >> 3) & 3) << 3;
      float4 a0 = *reinterpret_cast<const float4*>(&hT[kk][(tr * 4) ^ swz]);
      float4 a1 = *reinterpret_cast<const float4*>(&hT[kk][32 + ((tr * 4) ^ swz)]);
      float4 b0 = *reinterpret_cast<const float4*>(&Ws[kk][tc * 8]);
      float4 b1 = *reinterpret_cast<const float4*>(&Ws[kk][tc * 8 + 4]);
      float av0[4] = {a0.x, a0.y, a0.z, a0.w};
      float av1[4] = {a1.x, a1.y, a1.z, a1.w};
      float bb[8]  = {b0.x, b0.y, b0.z, b0.w, b1.x, b1.y, b1.z, b1.w};
#pragma unroll
      for (int i = 0; i < 4; ++i)
#pragma unroll
        for (int j = 0; j < 8; ++j) {
          acc[i][j]     += av0[i] * bb[j];
          acc[4 + i][j] += av1[i] * bb[j];
        }
    }
    __syncthreads();
  }

#pragma unroll
  for (int half = 0; half < 2; ++half) {
#pragma unroll
    for (int i = 0; i < 4; ++i) {
      int row = rowBase + half * 32 + tr * 4 + i;
      float nrm = src_norm[row];
      float* a = acc[half * 4 + i];
      uint4 v = {pack2bf(a[0] * nrm, a[1] * nrm), pack2bf(a[2] * nrm, a[3] * nrm),
                 pack2bf(a[4] * nrm, a[5] * nrm), pack2bf(a[6] * nrm, a[7] * nrm)};
      *reinterpret_cast<uint4*>(&out[(size_t)row * DOUT + tc * 8]) = v;
    }
  }
}

// ---------------- GEMM v7 (small DIN): lane=row, SGPR B, bf16 output ------------
template <int DIN, int DOUT>
__global__ __launch_bounds__(256) void k_gemm_v7(const float* __restrict__ h,
                                                 const float* __restrict__ src_norm,
                                                 const float* __restrict__ W,
                                                 unsigned short* __restrict__ out) {
  constexpr int KC   = 32;
  constexpr int ROWS = 64;
  constexpr int NCH  = DIN / KC;
  constexpr int CPW  = DOUT / 4;     // cols per wave
  __shared__ float hT[KC][ROWS];

  const int t    = threadIdx.x;
  const int lane = t & 63;
  const int wv   = __builtin_amdgcn_readfirstlane(t >> 6);
  const int rowBase = blockIdx.x * ROWS;
  const int rg0 = t >> 3;
  const int ks  = (t & 7) * 4;

  float acc[CPW];
#pragma unroll
  for (int j = 0; j < CPW; ++j) acc[j] = 0.0f;

  for (int ch = 0; ch < NCH; ++ch) {
    const int kc = ch * KC;
#pragma unroll
    for (int p = 0; p < 2; ++p) {
      int rg = rg0 + 32 * p;
      float4 v = *reinterpret_cast<const float4*>(&h[(size_t)(rowBase + rg) * DIN + kc + ks]);
      hT[ks + 0][rg ^ ((((ks + 0) >> 3) & 3) << 3)] = v.x;
      hT[ks + 1][rg ^ ((((ks + 1) >> 3) & 3) << 3)] = v.y;
      hT[ks + 2][rg ^ ((((ks + 2) >> 3) & 3) << 3)] = v.z;
      hT[ks + 3][rg ^ ((((ks + 3) >> 3) & 3) << 3)] = v.w;
    }
    __syncthreads();
    const float* Wrow = &W[(size_t)kc * DOUT + wv * CPW];  // wave-uniform base
#pragma unroll
    for (int kk = 0; kk < KC; ++kk) {
      const int swz = ((kk >> 3) & 3) << 3;
      float a = hT[kk][lane ^ swz];
#pragma unroll
      for (int j = 0; j < CPW; ++j)
        acc[j] += a * Wrow[kk * DOUT + j];   // uniform addr -> s_load
    }
    __syncthreads();
  }

  const int row = rowBase + lane;
  float nrm = src_norm[row];
  unsigned short* op = &out[(size_t)row * DOUT + wv * CPW];
  if constexpr (CPW == 8) {
    uint4 v = {pack2bf(acc[0] * nrm, acc[1] * nrm), pack2bf(acc[2] * nrm, acc[3] * nrm),
               pack2bf(acc[4] * nrm, acc[5] * nrm), pack2bf(acc[6] * nrm, acc[7] * nrm)};
    *reinterpret_cast<uint4*>(op) = v;
  } else {
    uint2 v = {pack2bf(acc[0] * nrm, acc[1] * nrm), pack2bf(acc[2] * nrm, acc[3] * nrm)};
    *reinterpret_cast<uint2*>(op) = v;
  }
}

// ---------------- aggregation (bf16 gathers): 4-deep unroll ---------------------
template <int D>
__global__ __launch_bounds__(256) void k_agg(const unsigned short* __restrict__ hw,
                                             const int* __restrict__ row_start,
                                             const int* __restrict__ csr_src,
                                             const float* __restrict__ dst_norm,
                                             const float* __restrict__ bias,
                                             float* __restrict__ out) {
  constexpr int LPN = D / 4;     // lanes per node (4 bf16 = 8B per lane)
  constexpr int NPW = 64 / LPN;  // nodes per wave
  const int t = threadIdx.x;
  const int lane = t & 63;
  const int wave = t >> 6;
  const int f4  = (lane % LPN) * 4;
  const int sub = lane / LPN;
  const int node = (blockIdx.x * 4 + wave) * NPW + sub;
  const int start = row_start[node];
  const int end   = row_start[node + 1];
  float ax = 0.0f, ay = 0.0f, az = 0.0f, aw = 0.0f;
  int i = start;
  for (; i + 4 <= end; i += 4) {
    int s0 = csr_src[i + 0];
    int s1 = csr_src[i + 1];
    int s2 = csr_src[i + 2];
    int s3 = csr_src[i + 3];
    ushort4 v0 = *reinterpret_cast<const ushort4*>(&hw[(size_t)s0 * D + f4]);
    ushort4 v1 = *reinterpret_cast<const ushort4*>(&hw[(size_t)s1 * D + f4]);
    ushort4 v2 = *reinterpret_cast<const ushort4*>(&hw[(size_t)s2 * D + f4]);
    ushort4 v3 = *reinterpret_cast<const ushort4*>(&hw[(size_t)s3 * D + f4]);
    ax += bf2f(v0.x) + bf2f(v1.x) + bf2f(v2.x) + bf2f(v3.x);
    ay += bf2f(v0.y) + bf2f(v1.y) + bf2f(v2.y) + bf2f(v3.y);
    az += bf2f(v0.z) + bf2f(v1.z) + bf2f(v2.z) + bf2f(v3.z);
    aw += bf2f(v0.w) + bf2f(v1.w) + bf2f(v2.w) + bf2f(v3.w);
  }
  for (; i < end; ++i) {
    ushort4 v = *reinterpret_cast<const ushort4*>(&hw[(size_t)csr_src[i] * D + f4]);
    ax += bf2f(v.x); ay += bf2f(v.y); az += bf2f(v.z); aw += bf2f(v.w);
  }
  float nrm = dst_norm[node];
  float4 b4 = *reinterpret_cast<const float4*>(&bias[f4]);
  float4 r;
  r.x = fmaxf(ax * nrm + b4.x, 0.0f);
  r.y = fmaxf(ay * nrm + b4.y, 0.0f);
  r.z = fmaxf(az * nrm + b4.z, 0.0f);
  r.w = fmaxf(aw * nrm + b4.w, 0.0f);
  *reinterpret_cast<float4*>(&out[(size_t)node * D + f4]) = r;
}

// ---------------- pooling ----------------
__global__ __launch_bounds__(256) void k_pool(const float* __restrict__ h3,
                                              const int* __restrict__ gid,
                                              float* __restrict__ sums,
                                              float* __restrict__ cnt) {
  const int t = threadIdx.x;
  const int f = t & 15;
  const int grp = t >> 4;
  const int base = blockIdx.x * POOL_NPB;
  float acc = 0.0f, c = 0.0f;
  int cur = gid[base + grp];
#pragma unroll 4
  for (int k = 0; k < POOL_NPB / 16; ++k) {
    int node = base + grp + k * 16;
    int g = gid[node];
    float v = h3[(size_t)node * 16 + f];
    if (g != cur) {
      atomicAdd(&sums[cur * 16 + f], acc);
      if (f == 0) atomicAdd(&cnt[cur], c);
      acc = 0.0f; c = 0.0f; cur = g;
    }
    acc += v; c += 1.0f;
  }
  atomicAdd(&sums[cur * 16 + f], acc);
  if (f == 0) atomicAdd(&cnt[cur], c);
}

__global__ __launch_bounds__(128) void k_classify(const float* __restrict__ sums,
                                                  const float* __restrict__ cnt,
                                                  const float* __restrict__ Wc,
                                                  const float* __restrict__ bc,
                                                  float* __restrict__ out) {
  int g = threadIdx.x;
  float c = cnt[g]; if (c < 1.0f) c = 1.0f;
  float acc = 0.0f;
#pragma unroll
  for (int f = 0; f < 16; ++f) acc += (sums[g * 16 + f] / c) * Wc[f];
  out[g] = acc + bc[0];
}

// ---------------- launch ----------------
extern "C" void kernel_launch(void* const* d_in, const int* in_sizes, int n_in,
                              void* d_out, int out_size, void* d_ws, size_t ws_size,
                              hipStream_t stream) {
  const float* features = (const float*)d_in[0];
  const int*   src      = (const int*)d_in[1];
  const int*   dst      = (const int*)d_in[2];
  const int*   gid      = (const int*)d_in[3];
  const float* W0 = (const float*)d_in[4];
  const float* b0 = (const float*)d_in[5];
  const float* W1 = (const float*)d_in[6];
  const float* b1 = (const float*)d_in[7];
  const float* W2 = (const float*)d_in[8];
  const float* b2 = (const float*)d_in[9];
  const float* Wc = (const float*)d_in[10];
  const float* bc = (const float*)d_in[11];
  float* out = (float*)d_out;

  char* w = (char*)d_ws;
  auto alloc = [&](size_t bytes) {
    void* p = (void*)w;
    w += (bytes + 255) & ~(size_t)255;
    return p;
  };
  float* src_norm    = (float*)alloc((size_t)N_NODES * 4);
  float* dst_norm    = (float*)alloc((size_t)N_NODES * 4);
  int*   row_start   = (int*)alloc((size_t)(N_NODES + 1) * 4);
  int*   cursor_d    = (int*)alloc(NB * 4);
  int*   cursor_s    = (int*)alloc(NB * 4);
  int*   bucket_base = (int*)alloc(NB * 4);
  int*   csr_src     = (int*)alloc((size_t)N_EDGES * 4);
  float* buf0        = (float*)alloc((size_t)N_NODES * 64 * 4);  // hw (bf16) / recs_d
  float* buf1        = (float*)alloc((size_t)N_NODES * 64 * 4);  // h (f32) / recs_s
  float* sums        = (float*)alloc((size_t)N_GRAPHS * 16 * 4);
  float* cnt         = (float*)alloc((size_t)N_GRAPHS * 4);
  unsigned int*   recs_d = (unsigned int*)buf0;
  unsigned short* recs_s = (unsigned short*)buf1;
  unsigned short* hw_bf  = (unsigned short*)buf0;   // bf16 hw, 16.7MB < 33.5MB
  float*          hbuf   = buf1;                    // f32 h

  hipMemsetAsync(sums, 0, (size_t)(N_GRAPHS * 16 + N_GRAPHS) * 4, stream);

  k_init_buckets<<<1, 256, 0, stream>>>(cursor_d, cursor_s);
  k_bin<<<N_EDGES / (256 * BIN_EPT), 256, 0, stream>>>(src, dst, cursor_d, cursor_s,
                                                       recs_d, recs_s);
  k_bucket_scan<<<1, 256, 0, stream>>>(cursor_d, bucket_base, row_start);
  k_graph<<<2 * NB, 512, 0, stream>>>(recs_d, cursor_d, recs_s, cursor_s,
                                      bucket_base, row_start, src_norm, dst_norm,
                                      csr_src);

  // layer 0: 256 -> 64 (v9, bf16 out)
  k_gemm_v9<256, 64><<<N_NODES / 64, 64, 0, stream>>>(features, src_norm, W0, hw_bf);
  k_agg<64><<<N_NODES / 16, 256, 0, stream>>>(hw_bf, row_start, csr_src, dst_norm, b0, hbuf);
  // layer 1: 64 -> 32 (v7, bf16 out)
  k_gemm_v7<64, 32><<<N_NODES / 64, 256, 0, stream>>>(hbuf, src_norm, W1, hw_bf);
  k_agg<32><<<N_NODES / 32, 256, 0, stream>>>(hw_bf, row_start, csr_src, dst_norm, b1, hbuf);
  // layer 2: 32 -> 16 (v7, bf16 out)
  k_gemm_v7<32, 16><<<N_NODES / 64, 256, 0, stream>>>(hbuf, src_norm, W2, hw_bf);
  k_agg<16><<<N_NODES / 64, 256, 0, stream>>>(hw_bf, row_start, csr_src, dst_norm, b2, hbuf);

  k_pool<<<N_NODES / POOL_NPB, 256, 0, stream>>>(hbuf, gid, sums, cnt);
  k_classify<<<1, 128, 0, stream>>>(sums, cnt, Wc, bc, out);
}

// Round 22
// 286.156 us; speedup vs baseline: 1.0386x; 1.0386x over previous
//
#include <hip/hip_runtime.h>

#define N_NODES 131072
#define N_EDGES 2097152
#define N_GRAPHS 128
#define POOL_NPB 256       // nodes per block in k_pool
#define NB 256             // buckets (both src- and dst-binning)
#define BUCKET_SHIFT 9     // 512 nodes per bucket
#define BUCKET_CAP 9728    // max edges per bucket (mean 8192, +17 sigma)
#define BIN_EPT 32         // edges per thread per pass in k_bin (8192/block)

__device__ __forceinline__ float bf2f(unsigned short b) {
  return __uint_as_float(((unsigned int)b) << 16);
}
__device__ __forceinline__ unsigned short f2bf(float f) {
  unsigned int u = __float_as_uint(f);
  return (unsigned short)((u + 0x7FFFu + ((u >> 16) & 1u)) >> 16);  // RTNE
}
__device__ __forceinline__ unsigned int pack2bf(float a, float b) {
  return (unsigned int)f2bf(a) | ((unsigned int)f2bf(b) << 16);
}

// ---------------- bucket cursor init ----------------
__global__ __launch_bounds__(256) void k_init_buckets(int* __restrict__ cursor_d,
                                                      int* __restrict__ cursor_s) {
  int i = threadIdx.x;
  cursor_d[i] = i * BUCKET_CAP;
  cursor_s[i] = i * BUCKET_CAP;
}

// ---------------- phase A: bin edges (two-pass, zero per-edge global atomics) ----
__global__ __launch_bounds__(256) void k_bin(const int* __restrict__ src,
                                             const int* __restrict__ dst,
                                             int* __restrict__ cursor_d,
                                             int* __restrict__ cursor_s,
                                             unsigned int* __restrict__ recs_d,
                                             unsigned short* __restrict__ recs_s) {
  __shared__ int hd[NB];
  __shared__ int hs[NB];
  const int t = threadIdx.x;
  const int e0 = blockIdx.x * (256 * BIN_EPT);
  hd[t] = 0; hs[t] = 0;
  __syncthreads();
#pragma unroll 4
  for (int k = 0; k < BIN_EPT; ++k) {
    int e = e0 + k * 256 + t;
    atomicAdd(&hd[dst[e] >> BUCKET_SHIFT], 1);
    atomicAdd(&hs[src[e] >> BUCKET_SHIFT], 1);
  }
  __syncthreads();
  { int c = hd[t]; hd[t] = c ? atomicAdd(&cursor_d[t], c) : 0; }
  { int c = hs[t]; hs[t] = c ? atomicAdd(&cursor_s[t], c) : 0; }
  __syncthreads();
#pragma unroll 4
  for (int k = 0; k < BIN_EPT; ++k) {
    int e = e0 + k * 256 + t;      // re-read (L2/L3 hot)
    int s = src[e];
    int d = dst[e];
    int pd = atomicAdd(&hd[d >> BUCKET_SHIFT], 1);
    recs_d[pd] = ((unsigned int)s << BUCKET_SHIFT) | (unsigned int)(d & 511);
    int ps = atomicAdd(&hs[s >> BUCKET_SHIFT], 1);
    recs_s[ps] = (unsigned short)(s & 511);
  }
}

// ---------------- outdeg via LDS histogram -> src_norm ----------------
__global__ __launch_bounds__(512) void k_outdeg(const unsigned short* __restrict__ recs_s,
                                                const int* __restrict__ cursor_s,
                                                float* __restrict__ src_norm) {
  __shared__ int hist[512];
  const int b = blockIdx.x;
  const int t = threadIdx.x;
  hist[t] = 0;
  __syncthreads();
  const int beg = b * BUCKET_CAP;
  const int end = cursor_s[b];
  for (int i = beg + t; i < end; i += 512) atomicAdd(&hist[recs_s[i]], 1);
  __syncthreads();
  int od = hist[t]; if (od < 1) od = 1;
  src_norm[b * 512 + t] = 1.0f / sqrtf((float)od);
}

// ---------------- bucket base: exclusive scan of dst-bucket counts ----------------
__global__ __launch_bounds__(256) void k_bucket_scan(const int* __restrict__ cursor_d,
                                                     int* __restrict__ bucket_base,
                                                     int* __restrict__ row_start) {
  __shared__ int tmp[256];
  int t = threadIdx.x;
  int c = cursor_d[t] - t * BUCKET_CAP;
  tmp[t] = c;
  __syncthreads();
  for (int off = 1; off < 256; off <<= 1) {
    int x = (t >= off) ? tmp[t - off] : 0;
    __syncthreads();
    tmp[t] += x;
    __syncthreads();
  }
  bucket_base[t] = tmp[t] - c;
  if (t == 0) row_start[N_NODES] = N_EDGES;
}

// ---------------- phase B: indeg+row_start+dst_norm+CSR fill, all in LDS --------
__global__ __launch_bounds__(512) void k_fill2(const unsigned int* __restrict__ recs_d,
                                               const int* __restrict__ cursor_d,
                                               const int* __restrict__ bucket_base,
                                               int* __restrict__ row_start,
                                               float* __restrict__ dst_norm,
                                               int* __restrict__ csr_src) {
  __shared__ int hist[512];
  __shared__ int lcur[512];
  const int b = blockIdx.x;
  const int t = threadIdx.x;
  hist[t] = 0;
  __syncthreads();
  const int beg = b * BUCKET_CAP;
  const int end = cursor_d[b];
  for (int i = beg + t; i < end; i += 512) atomicAdd(&hist[recs_d[i] & 511], 1);
  __syncthreads();
  int deg = hist[t];
  lcur[t] = deg;
  __syncthreads();
  for (int off = 1; off < 512; off <<= 1) {
    int x = (t >= off) ? lcur[t - off] : 0;
    __syncthreads();
    lcur[t] += x;
    __syncthreads();
  }
  int rs = bucket_base[b] + lcur[t] - deg;
  row_start[b * 512 + t] = rs;
  int dd = deg < 1 ? 1 : deg;
  dst_norm[b * 512 + t] = 1.0f / sqrtf((float)dd);
  lcur[t] = rs;
  __syncthreads();
  for (int i = beg + t; i < end; i += 512) {
    unsigned int r = recs_d[i];
    int p = atomicAdd(&lcur[r & 511], 1);
    csr_src[p] = (int)(r >> BUCKET_SHIFT);
  }
}

// ---------------- GEMM v9: 8x8 register tile, 1-wave blocks, bf16 output --------
template <int DIN, int DOUT>
__global__ __launch_bounds__(64) void k_gemm_v9(const float* __restrict__ h,
                                                const float* __restrict__ src_norm,
                                                const float* __restrict__ W,
                                                unsigned short* __restrict__ out) {
  constexpr int KC   = 32;
  constexpr int ROWS = 64;
  constexpr int HF4  = KC * ROWS / 4;
  constexpr int WF4  = KC * DOUT / 4;
  __shared__ float hT[KC][ROWS];
  __shared__ float Ws[KC][DOUT];

  const int t  = threadIdx.x;
  const int rowBase = blockIdx.x * ROWS;
  const int tr = t & 7;
  const int tc = t >> 3;

  float acc[8][8];
#pragma unroll
  for (int i = 0; i < 8; ++i)
#pragma unroll
    for (int j = 0; j < 8; ++j) acc[i][j] = 0.0f;

  for (int kc = 0; kc < DIN; kc += KC) {
#pragma unroll
    for (int p = 0; p < HF4 / 64; ++p) {
      int f = t + p * 64;
      int rg = f >> 3;
      int ks = (f & 7) * 4;
      float4 v = *reinterpret_cast<const float4*>(&h[(size_t)(rowBase + rg) * DIN + kc + ks]);
      hT[ks + 0][rg ^ ((((ks + 0) >> 3) & 3) << 3)] = v.x;
      hT[ks + 1][rg ^ ((((ks + 1) >> 3) & 3) << 3)] = v.y;
      hT[ks + 2][rg ^ ((((ks + 2) >> 3) & 3) << 3)] = v.z;
      hT[ks + 3][rg ^ ((((ks + 3) >> 3) & 3) << 3)] = v.w;
    }
#pragma unroll
    for (int p = 0; p < WF4 / 64; ++p) {
      int idx = (t + p * 64) * 4;
      *reinterpret_cast<float4*>(&Ws[0][0] + idx) =
          *reinterpret_cast<const float4*>(&W[(size_t)kc * DOUT + idx]);
    }
    __syncthreads();
#pragma unroll
    for (int kk = 0; kk < KC; ++kk) {
      const int swz = ((kk >> 3) & 3) << 3;
      float4 a0 = *reinterpret_cast<const float4*>(&hT[kk][(tr * 4) ^ swz]);
      float4 a1 = *reinterpret_cast<const float4*>(&hT[kk][32 + ((tr * 4) ^ swz)]);
      float4 b0 = *reinterpret_cast<const float4*>(&Ws[kk][tc * 8]);
      float4 b1 = *reinterpret_cast<const float4*>(&Ws[kk][tc * 8 + 4]);
      float av0[4] = {a0.x, a0.y, a0.z, a0.w};
      float av1[4] = {a1.x, a1.y, a1.z, a1.w};
      float bb[8]  = {b0.x, b0.y, b0.z, b0.w, b1.x, b1.y, b1.z, b1.w};
#pragma unroll
      for (int i = 0; i < 4; ++i)
#pragma unroll
        for (int j = 0; j < 8; ++j) {
          acc[i][j]     += av0[i] * bb[j];
          acc[4 + i][j] += av1[i] * bb[j];
        }
    }
    __syncthreads();
  }

#pragma unroll
  for (int half = 0; half < 2; ++half) {
#pragma unroll
    for (int i = 0; i < 4; ++i) {
      int row = rowBase + half * 32 + tr * 4 + i;
      float nrm = src_norm[row];
      float* a = acc[half * 4 + i];
      uint4 v = {pack2bf(a[0] * nrm, a[1] * nrm), pack2bf(a[2] * nrm, a[3] * nrm),
                 pack2bf(a[4] * nrm, a[5] * nrm), pack2bf(a[6] * nrm, a[7] * nrm)};
      *reinterpret_cast<uint4*>(&out[(size_t)row * DOUT + tc * 8]) = v;
    }
  }
}

// ---------------- GEMM v7 (small DIN): lane=row, SGPR B, bf16 output ------------
template <int DIN, int DOUT>
__global__ __launch_bounds__(256) void k_gemm_v7(const float* __restrict__ h,
                                                 const float* __restrict__ src_norm,
                                                 const float* __restrict__ W,
                                                 unsigned short* __restrict__ out) {
  constexpr int KC   = 32;
  constexpr int ROWS = 64;
  constexpr int NCH  = DIN / KC;
  constexpr int CPW  = DOUT / 4;     // cols per wave
  __shared__ float hT[KC][ROWS];

  const int t    = threadIdx.x;
  const int lane = t & 63;
  const int wv   = __builtin_amdgcn_readfirstlane(t >> 6);
  const int rowBase = blockIdx.x * ROWS;
  const int rg0 = t >> 3;
  const int ks  = (t & 7) * 4;

  float acc[CPW];
#pragma unroll
  for (int j = 0; j < CPW; ++j) acc[j] = 0.0f;

  for (int ch = 0; ch < NCH; ++ch) {
    const int kc = ch * KC;
#pragma unroll
    for (int p = 0; p < 2; ++p) {
      int rg = rg0 + 32 * p;
      float4 v = *reinterpret_cast<const float4*>(&h[(size_t)(rowBase + rg) * DIN + kc + ks]);
      hT[ks + 0][rg ^ ((((ks + 0) >> 3) & 3) << 3)] = v.x;
      hT[ks + 1][rg ^ ((((ks + 1) >> 3) & 3) << 3)] = v.y;
      hT[ks + 2][rg ^ ((((ks + 2) >> 3) & 3) << 3)] = v.z;
      hT[ks + 3][rg ^ ((((ks + 3) >> 3) & 3) << 3)] = v.w;
    }
    __syncthreads();
    const float* Wrow = &W[(size_t)kc * DOUT + wv * CPW];  // wave-uniform base
#pragma unroll
    for (int kk = 0; kk < KC; ++kk) {
      const int swz = ((kk >> 3) & 3) << 3;
      float a = hT[kk][lane ^ swz];
#pragma unroll
      for (int j = 0; j < CPW; ++j)
        acc[j] += a * Wrow[kk * DOUT + j];   // uniform addr -> s_load
    }
    __syncthreads();
  }

  const int row = rowBase + lane;
  float nrm = src_norm[row];
  unsigned short* op = &out[(size_t)row * DOUT + wv * CPW];
  if constexpr (CPW == 8) {
    uint4 v = {pack2bf(acc[0] * nrm, acc[1] * nrm), pack2bf(acc[2] * nrm, acc[3] * nrm),
               pack2bf(acc[4] * nrm, acc[5] * nrm), pack2bf(acc[6] * nrm, acc[7] * nrm)};
    *reinterpret_cast<uint4*>(op) = v;
  } else {
    uint2 v = {pack2bf(acc[0] * nrm, acc[1] * nrm), pack2bf(acc[2] * nrm, acc[3] * nrm)};
    *reinterpret_cast<uint2*>(op) = v;
  }
}

// ---------------- aggregation (bf16 gathers): 4-deep unroll ---------------------
template <int D>
__global__ __launch_bounds__(256) void k_agg(const unsigned short* __restrict__ hw,
                                             const int* __restrict__ row_start,
                                             const int* __restrict__ csr_src,
                                             const float* __restrict__ dst_norm,
                                             const float* __restrict__ bias,
                                             float* __restrict__ out) {
  constexpr int LPN = D / 4;     // lanes per node (4 bf16 = 8B per lane)
  constexpr int NPW = 64 / LPN;  // nodes per wave
  const int t = threadIdx.x;
  const int lane = t & 63;
  const int wave = t >> 6;
  const int f4  = (lane % LPN) * 4;
  const int sub = lane / LPN;
  const int node = (blockIdx.x * 4 + wave) * NPW + sub;
  const int start = row_start[node];
  const int end   = row_start[node + 1];
  float ax = 0.0f, ay = 0.0f, az = 0.0f, aw = 0.0f;
  int i = start;
  for (; i + 4 <= end; i += 4) {
    int s0 = csr_src[i + 0];
    int s1 = csr_src[i + 1];
    int s2 = csr_src[i + 2];
    int s3 = csr_src[i + 3];
    ushort4 v0 = *reinterpret_cast<const ushort4*>(&hw[(size_t)s0 * D + f4]);
    ushort4 v1 = *reinterpret_cast<const ushort4*>(&hw[(size_t)s1 * D + f4]);
    ushort4 v2 = *reinterpret_cast<const ushort4*>(&hw[(size_t)s2 * D + f4]);
    ushort4 v3 = *reinterpret_cast<const ushort4*>(&hw[(size_t)s3 * D + f4]);
    ax += bf2f(v0.x) + bf2f(v1.x) + bf2f(v2.x) + bf2f(v3.x);
    ay += bf2f(v0.y) + bf2f(v1.y) + bf2f(v2.y) + bf2f(v3.y);
    az += bf2f(v0.z) + bf2f(v1.z) + bf2f(v2.z) + bf2f(v3.z);
    aw += bf2f(v0.w) + bf2f(v1.w) + bf2f(v2.w) + bf2f(v3.w);
  }
  for (; i < end; ++i) {
    ushort4 v = *reinterpret_cast<const ushort4*>(&hw[(size_t)csr_src[i] * D + f4]);
    ax += bf2f(v.x); ay += bf2f(v.y); az += bf2f(v.z); aw += bf2f(v.w);
  }
  float nrm = dst_norm[node];
  float4 b4 = *reinterpret_cast<const float4*>(&bias[f4]);
  float4 r;
  r.x = fmaxf(ax * nrm + b4.x, 0.0f);
  r.y = fmaxf(ay * nrm + b4.y, 0.0f);
  r.z = fmaxf(az * nrm + b4.z, 0.0f);
  r.w = fmaxf(aw * nrm + b4.w, 0.0f);
  *reinterpret_cast<float4*>(&out[(size_t)node * D + f4]) = r;
}

// ---------------- pooling ----------------
__global__ __launch_bounds__(256) void k_pool(const float* __restrict__ h3,
                                              const int* __restrict__ gid,
                                              float* __restrict__ sums,
                                              float* __restrict__ cnt) {
  const int t = threadIdx.x;
  const int f = t & 15;
  const int grp = t >> 4;
  const int base = blockIdx.x * POOL_NPB;
  float acc = 0.0f, c = 0.0f;
  int cur = gid[base + grp];
#pragma unroll 4
  for (int k = 0; k < POOL_NPB / 16; ++k) {
    int node = base + grp + k * 16;
    int g = gid[node];
    float v = h3[(size_t)node * 16 + f];
    if (g != cur) {
      atomicAdd(&sums[cur * 16 + f], acc);
      if (f == 0) atomicAdd(&cnt[cur], c);
      acc = 0.0f; c = 0.0f; cur = g;
    }
    acc += v; c += 1.0f;
  }
  atomicAdd(&sums[cur * 16 + f], acc);
  if (f == 0) atomicAdd(&cnt[cur], c);
}

__global__ __launch_bounds__(128) void k_classify(const float* __restrict__ sums,
                                                  const float* __restrict__ cnt,
                                                  const float* __restrict__ Wc,
                                                  const float* __restrict__ bc,
                                                  float* __restrict__ out) {
  int g = threadIdx.x;
  float c = cnt[g]; if (c < 1.0f) c = 1.0f;
  float acc = 0.0f;
#pragma unroll
  for (int f = 0; f < 16; ++f) acc += (sums[g * 16 + f] / c) * Wc[f];
  out[g] = acc + bc[0];
}

// ---------------- launch ----------------
extern "C" void kernel_launch(void* const* d_in, const int* in_sizes, int n_in,
                              void* d_out, int out_size, void* d_ws, size_t ws_size,
                              hipStream_t stream) {
  const float* features = (const float*)d_in[0];
  const int*   src      = (const int*)d_in[1];
  const int*   dst      = (const int*)d_in[2];
  const int*   gid      = (const int*)d_in[3];
  const float* W0 = (const float*)d_in[4];
  const float* b0 = (const float*)d_in[5];
  const float* W1 = (const float*)d_in[6];
  const float* b1 = (const float*)d_in[7];
  const float* W2 = (const float*)d_in[8];
  const float* b2 = (const float*)d_in[9];
  const float* Wc = (const float*)d_in[10];
  const float* bc = (const float*)d_in[11];
  float* out = (float*)d_out;

  char* w = (char*)d_ws;
  auto alloc = [&](size_t bytes) {
    void* p = (void*)w;
    w += (bytes + 255) & ~(size_t)255;
    return p;
  };
  float* src_norm    = (float*)alloc((size_t)N_NODES * 4);
  float* dst_norm    = (float*)alloc((size_t)N_NODES * 4);
  int*   row_start   = (int*)alloc((size_t)(N_NODES + 1) * 4);
  int*   cursor_d    = (int*)alloc(NB * 4);
  int*   cursor_s    = (int*)alloc(NB * 4);
  int*   bucket_base = (int*)alloc(NB * 4);
  int*   csr_src     = (int*)alloc((size_t)N_EDGES * 4);
  float* buf0        = (float*)alloc((size_t)N_NODES * 64 * 4);  // hw (bf16) / recs_d
  float* buf1        = (float*)alloc((size_t)N_NODES * 64 * 4);  // h (f32) / recs_s
  float* sums        = (float*)alloc((size_t)N_GRAPHS * 16 * 4);
  float* cnt         = (float*)alloc((size_t)N_GRAPHS * 4);
  unsigned int*   recs_d = (unsigned int*)buf0;
  unsigned short* recs_s = (unsigned short*)buf1;
  unsigned short* hw_bf  = (unsigned short*)buf0;   // bf16 hw, 16.7MB < 33.5MB
  float*          hbuf   = buf1;                    // f32 h

  hipMemsetAsync(sums, 0, (size_t)(N_GRAPHS * 16 + N_GRAPHS) * 4, stream);

  k_init_buckets<<<1, 256, 0, stream>>>(cursor_d, cursor_s);
  k_bin<<<N_EDGES / (256 * BIN_EPT), 256, 0, stream>>>(src, dst, cursor_d, cursor_s,
                                                       recs_d, recs_s);
  k_outdeg<<<NB, 512, 0, stream>>>(recs_s, cursor_s, src_norm);
  k_bucket_scan<<<1, 256, 0, stream>>>(cursor_d, bucket_base, row_start);
  k_fill2<<<NB, 512, 0, stream>>>(recs_d, cursor_d, bucket_base, row_start,
                                  dst_norm, csr_src);

  // layer 0: 256 -> 64 (v9, bf16 out)
  k_gemm_v9<256, 64><<<N_NODES / 64, 64, 0, stream>>>(features, src_norm, W0, hw_bf);
  k_agg<64><<<N_NODES / 16, 256, 0, stream>>>(hw_bf, row_start, csr_src, dst_norm, b0, hbuf);
  // layer 1: 64 -> 32 (v7, bf16 out)
  k_gemm_v7<64, 32><<<N_NODES / 64, 256, 0, stream>>>(hbuf, src_norm, W1, hw_bf);
  k_agg<32><<<N_NODES / 32, 256, 0, stream>>>(hw_bf, row_start, csr_src, dst_norm, b1, hbuf);
  // layer 2: 32 -> 16 (v7, bf16 out)
  k_gemm_v7<32, 16><<<N_NODES / 64, 256, 0, stream>>>(hbuf, src_norm, W2, hw_bf);
  k_agg<16><<<N_NODES / 64, 256, 0, stream>>>(hw_bf, row_start, csr_src, dst_norm, b2, hbuf);

  k_pool<<<N_NODES / POOL_NPB, 256, 0, stream>>>(hbuf, gid, sums, cnt);
  k_classify<<<1, 128, 0, stream>>>(sums, cnt, Wc, bc, out);
}